// Round 10
// baseline (1252.629 us; speedup 1.0000x reference)
//
#include <hip/hip_runtime.h>
#include <hip/hip_bf16.h>

static constexpr int S = 64, T = 64, B = 64, E = 256, H = 256, V = 32000;
static constexpr int H4 = 4 * H;          // 1024
static constexpr int NCHUNK = 500;        // V / 64
static constexpr int NROW = (T - 1) * B;  // 4032
static constexpr int LDP = 264;           // LDS row stride (bf16) for MFMA staging tiles

typedef short bf16x8 __attribute__((ext_vector_type(8)));
typedef float f32x4 __attribute__((ext_vector_type(4)));
typedef unsigned long long ull;

__device__ __forceinline__ float sigf(float x) { return 1.0f / (1.0f + __expf(-x)); }
__device__ __forceinline__ float tanhfast(float x) { return 1.0f - 2.0f / (__expf(2.0f * x) + 1.0f); }
__device__ __forceinline__ float bflo(uint w) { return __uint_as_float(w << 16); }
__device__ __forceinline__ float bfhi(uint w) { return __uint_as_float(w & 0xffff0000u); }
__device__ __forceinline__ ushort f2bu(float x) {
  return __bfloat16_as_ushort(__float2bfloat16(x));
}

// ---- relaxed agent-scope (cache-bypassing, NO wbl2/inv) primitives ----
__device__ __forceinline__ void st_u32(uint* p, uint v) {
  __hip_atomic_store(p, v, __ATOMIC_RELAXED, __HIP_MEMORY_SCOPE_AGENT);
}
__device__ __forceinline__ uint ld_u32(const uint* p) {
  return __hip_atomic_load(p, __ATOMIC_RELAXED, __HIP_MEMORY_SCOPE_AGENT);
}
// NOTE: data stores are uncached; the __syncthreads() before a flag post drains
// each wave's vmcnt (compiler-inserted s_waitcnt before s_barrier) so data is at
// the coherence point before the flag becomes visible.

// ---------------- small utility kernels ----------------
__global__ __launch_bounds__(256) void k_cvt_bf16(const float* __restrict__ src,
                                                  __hip_bfloat16* __restrict__ dst, int n) {
  int i = blockIdx.x * 256 + threadIdx.x;
  if (i < n) dst[i] = __float2bfloat16(src[i]);
}

__global__ __launch_bounds__(256) void k_cvt_slice(const float* __restrict__ src,
                                                   __hip_bfloat16* __restrict__ dst) {
  int n = blockIdx.x, tid = threadIdx.x;
  dst[n * 256 + tid] = __float2bfloat16(src[n * 512 + tid]);
}

__global__ __launch_bounds__(256) void k_gather(const int* __restrict__ idx,
                                                const float* __restrict__ emb,
                                                __hip_bfloat16* __restrict__ dst) {
  int r = blockIdx.x, tid = threadIdx.x;
  dst[r * 256 + tid] = __float2bfloat16(emb[idx[r] * E + tid]);
}

// quad-k pack: dst[i][j] = bf16 src[j][4i..4i+3]  (uint2 [K/4][J])
__global__ __launch_bounds__(256) void k_pack4(const float* __restrict__ src,
                                               uint2* __restrict__ dst,
                                               int total, int jshift, int ld, int off) {
  int idx = blockIdx.x * 256 + threadIdx.x;
  if (idx >= total) return;
  int J = 1 << jshift;
  int i = idx >> jshift, j = idx & (J - 1);
  const float* s = src + (size_t)j * ld + off + 4 * i;
  float4 v = *(const float4*)s;
  uint2 o;
  o.x = (uint)f2bu(v.x) | ((uint)f2bu(v.y) << 16);
  o.y = (uint)f2bu(v.z) | ((uint)f2bu(v.w) << 16);
  dst[(size_t)i * J + j] = o;
}

// ============ shared MFMA 64x64 tile core (K=256, bf16 in, f32 acc) ===========
#define MFMA_TILE_BODY(Abase, Wbase, rb, cb)                                     \
  const int tid = threadIdx.x;                                                   \
  const int lane = tid & 63, wid = tid >> 6;                                     \
  const int wr = wid >> 1, wc = wid & 1;                                         \
  const int l15 = lane & 15, l4 = lane >> 4;                                     \
  for (int it = 0; it < 8; it++) {                                               \
    int c = it * 256 + tid;                                                      \
    int row = c >> 5, off = (c & 31) * 8;                                        \
    *(uint4*)&Asl[row * LDP + off] =                                             \
        *(const uint4*)((Abase) + (size_t)((rb) + row) * 256 + off);             \
    *(uint4*)&Bsl[row * LDP + off] =                                             \
        *(const uint4*)((Wbase) + (size_t)((cb) + row) * 256 + off);             \
  }                                                                              \
  __syncthreads();                                                               \
  f32x4 acc[2][2];                                                               \
  for (int m = 0; m < 2; m++)                                                    \
    for (int n = 0; n < 2; n++) acc[m][n] = (f32x4){0.f, 0.f, 0.f, 0.f};         \
  for (int kk = 0; kk < 8; kk++) {                                               \
    int ko = kk * 32 + l4 * 8;                                                   \
    bf16x8 a0 = *(const bf16x8*)&Asl[(wr * 32 + l15) * LDP + ko];                \
    bf16x8 a1 = *(const bf16x8*)&Asl[(wr * 32 + 16 + l15) * LDP + ko];           \
    bf16x8 b0 = *(const bf16x8*)&Bsl[(wc * 32 + l15) * LDP + ko];                \
    bf16x8 b1 = *(const bf16x8*)&Bsl[(wc * 32 + 16 + l15) * LDP + ko];           \
    acc[0][0] = __builtin_amdgcn_mfma_f32_16x16x32_bf16(a0, b0, acc[0][0], 0, 0, 0); \
    acc[0][1] = __builtin_amdgcn_mfma_f32_16x16x32_bf16(a0, b1, acc[0][1], 0, 0, 0); \
    acc[1][0] = __builtin_amdgcn_mfma_f32_16x16x32_bf16(a1, b0, acc[1][0], 0, 0, 0); \
    acc[1][1] = __builtin_amdgcn_mfma_f32_16x16x32_bf16(a1, b1, acc[1][1], 0, 0, 0); \
  }

// ---------------- generic GEMM + bias -----------------------------------------
__global__ __launch_bounds__(256) void k_gemm_bias(
    const __hip_bfloat16* __restrict__ A, const __hip_bfloat16* __restrict__ W,
    const float* __restrict__ bias, float* __restrict__ C, int ldc) {
  __shared__ __align__(16) ushort Asl[64 * LDP];
  __shared__ __align__(16) ushort Bsl[64 * LDP];
  const int cb = blockIdx.x * 64, rb = blockIdx.y * 64;
  MFMA_TILE_BODY((const ushort*)A, (const ushort*)W, rb, cb)
  #pragma unroll
  for (int m = 0; m < 2; m++)
    #pragma unroll
    for (int n = 0; n < 2; n++) {
      int col = cb + wc * 32 + n * 16 + l15;
      float bv = bias[col];
      #pragma unroll
      for (int r = 0; r < 4; r++) {
        int row = rb + wr * 32 + m * 16 + l4 * 4 + r;
        C[(size_t)row * ldc + col] = acc[m][n][r] + bv;
      }
    }
}

// ---------------- enc_proj as MFMA GEMM: 4096x256, K=512 ----------------------
__global__ __launch_bounds__(256) void k_encproj_mfma(
    const __hip_bfloat16* __restrict__ fwd_bf, const __hip_bfloat16* __restrict__ bwd_bf,
    const __hip_bfloat16* __restrict__ Watt_bf, __hip_bfloat16* __restrict__ encproj_bf) {
  __shared__ __align__(16) ushort Asl[64 * LDP];
  __shared__ __align__(16) ushort Bsl[64 * LDP];
  const int cb = blockIdx.x * 64, rb = blockIdx.y * 64;
  const int tid = threadIdx.x;
  const int lane = tid & 63, wid = tid >> 6;
  const int wr = wid >> 1, wc = wid & 1;
  const int l15 = lane & 15, l4 = lane >> 4;
  f32x4 acc[2][2];
  #pragma unroll
  for (int m = 0; m < 2; m++)
    #pragma unroll
    for (int n = 0; n < 2; n++) acc[m][n] = (f32x4){0.f, 0.f, 0.f, 0.f};
  for (int kt = 0; kt < 2; kt++) {
    if (kt) __syncthreads();
    for (int it = 0; it < 8; it++) {
      int c = it * 256 + tid;
      int row = c >> 5, off = (c & 31) * 8;
      int r = rb + row, s = r >> 6, bb = r & 63;
      const ushort* arow = (kt == 0)
          ? (const ushort*)fwd_bf + (size_t)(s * 64 + bb) * 256
          : (const ushort*)bwd_bf + (size_t)(s * 64 + bb) * 256;
      *(uint4*)&Asl[row * LDP + off] = *(const uint4*)(arow + off);
      *(uint4*)&Bsl[row * LDP + off] =
          *(const uint4*)((const ushort*)Watt_bf + (size_t)(cb + row) * 512 + kt * 256 + off);
    }
    __syncthreads();
    for (int kk = 0; kk < 8; kk++) {
      int ko = kk * 32 + l4 * 8;
      bf16x8 a0 = *(const bf16x8*)&Asl[(wr * 32 + l15) * LDP + ko];
      bf16x8 a1 = *(const bf16x8*)&Asl[(wr * 32 + 16 + l15) * LDP + ko];
      bf16x8 b0 = *(const bf16x8*)&Bsl[(wc * 32 + l15) * LDP + ko];
      bf16x8 b1 = *(const bf16x8*)&Bsl[(wc * 32 + 16 + l15) * LDP + ko];
      acc[0][0] = __builtin_amdgcn_mfma_f32_16x16x32_bf16(a0, b0, acc[0][0], 0, 0, 0);
      acc[0][1] = __builtin_amdgcn_mfma_f32_16x16x32_bf16(a0, b1, acc[0][1], 0, 0, 0);
      acc[1][0] = __builtin_amdgcn_mfma_f32_16x16x32_bf16(a1, b0, acc[1][0], 0, 0, 0);
      acc[1][1] = __builtin_amdgcn_mfma_f32_16x16x32_bf16(a1, b1, acc[1][1], 0, 0, 0);
    }
  }
  #pragma unroll
  for (int m = 0; m < 2; m++)
    #pragma unroll
    for (int n = 0; n < 2; n++) {
      int col = cb + wc * 32 + n * 16 + l15;
      #pragma unroll
      for (int r = 0; r < 4; r++) {
        int row = rb + wr * 32 + m * 16 + l4 * 4 + r;
        int s = row >> 6, bb = row & 63;
        ((ushort*)encproj_bf)[(size_t)(bb * 64 + s) * 256 + col] = f2bu(acc[m][n][r]);
      }
    }
}

// ---------------- vocab: B-stationary, loop over t ----------------------------
__global__ __launch_bounds__(256) void k_vocab2(
    const __hip_bfloat16* __restrict__ outs_bf, const __hip_bfloat16* __restrict__ Wv,
    const int* __restrict__ tgt, float* __restrict__ part_max,
    float* __restrict__ part_sum, float* __restrict__ gold) {
  __shared__ __align__(16) ushort Asl[64 * LDP];
  __shared__ __align__(16) ushort Bsl[64 * LDP];
  __shared__ int goldcol[64];
  __shared__ float pm[64][2], ps[64][2];
  const int vb = blockIdx.x;
  const int tid = threadIdx.x;
  const int lane = tid & 63, wid = tid >> 6;
  const int wr = wid >> 1, wc = wid & 1;
  const int l15 = lane & 15, l4 = lane >> 4;
  for (int it = 0; it < 8; it++) {
    int c = it * 256 + tid;
    int row = c >> 5, off = (c & 31) * 8;
    *(uint4*)&Bsl[row * LDP + off] =
        *(const uint4*)((const ushort*)Wv + (size_t)(vb * 64 + row) * 256 + off);
  }
  for (int t = 0; t < T - 1; t++) {
    __syncthreads();
    for (int it = 0; it < 8; it++) {
      int c = it * 256 + tid;
      int row = c >> 5, off = (c & 31) * 8;
      *(uint4*)&Asl[row * LDP + off] =
          *(const uint4*)((const ushort*)outs_bf + (size_t)(t * 64 + row) * 256 + off);
    }
    if (tid < 64) goldcol[tid] = tgt[(t + 1) * B + tid];
    __syncthreads();
    f32x4 acc[2][2];
    #pragma unroll
    for (int m = 0; m < 2; m++)
      #pragma unroll
      for (int n = 0; n < 2; n++) acc[m][n] = (f32x4){0.f, 0.f, 0.f, 0.f};
    for (int kk = 0; kk < 8; kk++) {
      int ko = kk * 32 + l4 * 8;
      bf16x8 a0 = *(const bf16x8*)&Asl[(wr * 32 + l15) * LDP + ko];
      bf16x8 a1 = *(const bf16x8*)&Asl[(wr * 32 + 16 + l15) * LDP + ko];
      bf16x8 b0 = *(const bf16x8*)&Bsl[(wc * 32 + l15) * LDP + ko];
      bf16x8 b1 = *(const bf16x8*)&Bsl[(wc * 32 + 16 + l15) * LDP + ko];
      acc[0][0] = __builtin_amdgcn_mfma_f32_16x16x32_bf16(a0, b0, acc[0][0], 0, 0, 0);
      acc[0][1] = __builtin_amdgcn_mfma_f32_16x16x32_bf16(a0, b1, acc[0][1], 0, 0, 0);
      acc[1][0] = __builtin_amdgcn_mfma_f32_16x16x32_bf16(a1, b0, acc[1][0], 0, 0, 0);
      acc[1][1] = __builtin_amdgcn_mfma_f32_16x16x32_bf16(a1, b1, acc[1][1], 0, 0, 0);
    }
    #pragma unroll
    for (int m = 0; m < 2; m++) {
      #pragma unroll
      for (int r = 0; r < 4; r++) {
        int row_local = wr * 32 + m * 16 + l4 * 4 + r;
        int gc = goldcol[row_local];
        #pragma unroll
        for (int n = 0; n < 2; n++) {
          int col = vb * 64 + wc * 32 + n * 16 + l15;
          if (col == gc) gold[t * 64 + row_local] = acc[m][n][r];
        }
        float v = fmaxf(acc[m][0][r], acc[m][1][r]);
        #pragma unroll
        for (int o = 1; o < 16; o <<= 1) v = fmaxf(v, __shfl_xor(v, o));
        float e = __expf(acc[m][0][r] - v) + __expf(acc[m][1][r] - v);
        #pragma unroll
        for (int o = 1; o < 16; o <<= 1) e += __shfl_xor(e, o);
        if (l15 == 0) { pm[row_local][wc] = v; ps[row_local][wc] = e; }
      }
    }
    __syncthreads();
    if (tid < 64) {
      float m0 = pm[tid][0], m1 = pm[tid][1];
      float M = fmaxf(m0, m1);
      float Ss = ps[tid][0] * __expf(m0 - M) + ps[tid][1] * __expf(m1 - M);
      part_max[(size_t)vb * NROW + t * 64 + tid] = M;
      part_sum[(size_t)vb * NROW + t * 64 + tid] = Ss;
    }
  }
}

// ---------------- encoder: 128 blocks, XCD-local octets, uncached exchange ----
__global__ __launch_bounds__(256) void k_enc4(
    const float* __restrict__ XwF, const float* __restrict__ XwB,
    const float* __restrict__ WhhF, const float* __restrict__ WhhB,
    uint* __restrict__ Xenc_u32,
    __hip_bfloat16* __restrict__ fwd_bf, __hip_bfloat16* __restrict__ bwd_bf,
    float* __restrict__ Cfin, uint* __restrict__ eflags) {
  __shared__ __align__(16) ushort Wl[128 * 264];  // 67584 B
  __shared__ __align__(16) ushort Xa[16 * 264];   // 8448 B
  __shared__ float zz[4][8][33];
  __shared__ float hsb[8][32];
  const int id = blockIdx.x;
  const int g = id & 7, kb = id >> 3;
  const int dir = kb >> 3, s = kb & 7;
  const int tid = threadIdx.x;
  const float* Whh = dir ? WhhB : WhhF;
  const float* Xw = dir ? XwB : XwF;
  uint* fl = eflags + (size_t)(g * 2 + dir) * 8 * 32;
  for (int i = tid; i < 128 * 256; i += 256) {
    int c = i >> 8, k2 = i & 255;
    int gate = c >> 5, jj = c & 31;
    Wl[c * 264 + k2] = f2bu(Whh[(size_t)(gate * 256 + s * 32 + jj) * 256 + k2]);
  }
  for (int i = tid; i < 16 * 264; i += 256) Xa[i] = 0;
  const int lane = tid & 63, w = tid >> 6;   // wave = gate
  const int l15 = lane & 15, l4 = lane >> 4;
  const int tb = tid >> 5, tjj = tid & 31;
  float c_reg = 0.f;
  __syncthreads();
  for (int st = 0; st < 64; st++) {
    const int ts = dir ? 63 - st : st;
    const int par = st & 1;
    const uint* Xr = Xenc_u32 + (size_t)(par * 2 + dir) * 8192;
    uint* Xo = Xenc_u32 + (size_t)((par ^ 1) * 2 + dir) * 8192;
    for (int i = tid; i < 8 * 128; i += 256) {
      int row = i >> 7, colu = i & 127;
      uint v = ld_u32(Xr + (size_t)(8 * g + row) * 128 + colu);
      *(uint*)&Xa[row * 264 + colu * 2] = v;
    }
    __syncthreads();
    f32x4 a0v = (f32x4){0.f, 0.f, 0.f, 0.f}, a1v = (f32x4){0.f, 0.f, 0.f, 0.f};
    for (int kk = 0; kk < 8; kk++) {
      bf16x8 af = *(const bf16x8*)&Xa[l15 * 264 + kk * 32 + l4 * 8];
      bf16x8 b0 = *(const bf16x8*)&Wl[((2 * w) * 16 + l15) * 264 + kk * 32 + l4 * 8];
      bf16x8 b1 = *(const bf16x8*)&Wl[((2 * w + 1) * 16 + l15) * 264 + kk * 32 + l4 * 8];
      a0v = __builtin_amdgcn_mfma_f32_16x16x32_bf16(af, b0, a0v, 0, 0, 0);
      a1v = __builtin_amdgcn_mfma_f32_16x16x32_bf16(af, b1, a1v, 0, 0, 0);
    }
    if (l4 < 2) {
      #pragma unroll
      for (int r = 0; r < 4; r++) {
        int b = l4 * 4 + r;
        zz[w][b][l15] = a0v[r];
        zz[w][b][16 + l15] = a1v[r];
      }
    }
    __syncthreads();
    {
      int gb = 8 * g + tb, j = 32 * s + tjj;
      const float* xw = Xw + (size_t)(ts * 64 + gb) * 1024;
      float zi = zz[0][tb][tjj] + xw[j];
      float zf = zz[1][tb][tjj] + xw[256 + j];
      float zg = zz[2][tb][tjj] + xw[512 + j];
      float zo = zz[3][tb][tjj] + xw[768 + j];
      float c = sigf(zf) * c_reg + sigf(zi) * tanhfast(zg);
      c_reg = c;
      float h = sigf(zo) * tanhfast(c);
      hsb[tb][tjj] = h;
      ushort hb = f2bu(h);
      if (dir == 0) ((ushort*)fwd_bf)[(size_t)(st * 64 + gb) * 256 + j] = hb;
      else          ((ushort*)bwd_bf)[(size_t)((63 - st) * 64 + gb) * 256 + j] = hb;
    }
    __syncthreads();
    if (tid < 128) {  // packed uncached h store (2 bf16 per uint)
      int tb2 = tid >> 4, p = tid & 15;
      uint v = (uint)f2bu(hsb[tb2][2 * p]) | ((uint)f2bu(hsb[tb2][2 * p + 1]) << 16);
      st_u32(Xo + (size_t)(8 * g + tb2) * 128 + 16 * s + p, v);
    }
    __syncthreads();  // drains vmcnt -> uncached stores at coherence point
    if (tid == 0) st_u32(&fl[s * 32], (uint)(st + 1));
    if (tid < 8)
      while (ld_u32(&fl[tid * 32]) < (uint)(st + 1)) __builtin_amdgcn_s_sleep(2);
    asm volatile("" ::: "memory");
    __syncthreads();
  }
  Cfin[(size_t)(dir * 64 + 8 * g + tb) * 256 + 32 * s + tjj] = c_reg;
}

// ---------------- decoder init: dec_h/dec_c + packed Xd[0] --------------------
__global__ __launch_bounds__(256) void k_dec_init3(
    const __hip_bfloat16* __restrict__ Xenc, const float* __restrict__ Cfin,
    const float* __restrict__ Wh, const float* __restrict__ Wc,
    uint* __restrict__ Xd_u32, float* __restrict__ decc0) {
  int b = blockIdx.x, tid = threadIdx.x;
  __shared__ __align__(16) float ch[512], cc[512];
  __shared__ float hh[256];
  ch[tid]       = __bfloat162float(Xenc[(size_t)(0 * 64 + b) * 256 + tid]);
  ch[256 + tid] = __bfloat162float(Xenc[(size_t)(1 * 64 + b) * 256 + tid]);
  cc[tid]       = Cfin[(size_t)(0 * 64 + b) * 256 + tid];
  cc[256 + tid] = Cfin[(size_t)(1 * 64 + b) * 256 + tid];
  __syncthreads();
  const float* wh = Wh + tid * 512;
  const float* wc = Wc + tid * 512;
  float ah = 0, ac = 0;
  for (int k = 0; k < 512; k += 4) {
    float4 hv = *(const float4*)&ch[k];
    float4 cv = *(const float4*)&cc[k];
    float4 w1 = *(const float4*)&wh[k];
    float4 w2 = *(const float4*)&wc[k];
    ah += hv.x * w1.x + hv.y * w1.y + hv.z * w1.z + hv.w * w1.w;
    ac += cv.x * w2.x + cv.y * w2.y + cv.z * w2.z + cv.w * w2.w;
  }
  decc0[b * 256 + tid] = ac;
  hh[tid] = ah;
  __syncthreads();
  if (tid < 128) {
    uint v = (uint)f2bu(hh[2 * tid]) | ((uint)f2bu(hh[2 * tid + 1]) << 16);
    Xd_u32[(size_t)b * 256 + tid] = v;          // h(0) packed
    Xd_u32[(size_t)b * 256 + 128 + tid] = 0u;   // O(0) = 0
  }
}

// ---------------- decoder: 192 blocks; z-blocks own gates + h -----------------
// id: g = id&7 (XCD), kb = id>>3. kb<8: z-block slice s=kb owns j in
// [32s,32s+32) x 4 gates (128 cols x 512 k stationary), c in registers,
// posts packed h-slice into Xd. kb>=8: att block b=8g+lb, O-half jh.
// Xd: [par][b][256 uints] = [h(128u)|O(128u)] bf16-pair packed.
__global__ __launch_bounds__(512) void k_dec5(
    const float* __restrict__ YW, const float* __restrict__ dWih,
    const float* __restrict__ dWhh, const uint2* __restrict__ Wcq,
    const __hip_bfloat16* __restrict__ encproj_bf,
    const __hip_bfloat16* __restrict__ fwd_bf, const __hip_bfloat16* __restrict__ bwd_bf,
    const float* __restrict__ decc0, uint* __restrict__ Xd_u32,
    __hip_bfloat16* __restrict__ outs_bf,
    uint* __restrict__ zflags, uint* __restrict__ aflags) {
  __shared__ __align__(16) char smem[155648];
  const int id = blockIdx.x;
  const int g = id & 7, kb = id >> 3;
  const int tid = threadIdx.x;
  uint* zfl = zflags + (size_t)g * 8 * 32;
  uint* afl = aflags + (size_t)g * 16 * 32;

  if (kb < 8) {
    // ------------- z-block: j-slice [32s,32s+32) x 4 gates, gates + h --------
    const int s = kb;
    ushort* Wl = (ushort*)smem;                    // [128][520] = 133120 B
    ushort* Xa = (ushort*)(smem + 133120);         // [16][520] = 16640 B
    float* zslds = (float*)(smem + 149760);        // [8][128] = 4096 B
    float* hsb = (float*)(smem + 153856);          // [8][32] = 1024 B
    for (int i = tid; i < 128 * 512; i += 512) {
      int c = i >> 9, k2 = i & 511;
      int gate = c >> 5, jj = c & 31;
      int gr = gate * 256 + 32 * s + jj;
      float v = (k2 < 256) ? dWhh[(size_t)gr * 256 + k2]
                           : dWih[(size_t)gr * 512 + 256 + (k2 - 256)];
      Wl[c * 520 + k2] = f2bu(v);
    }
    for (int i = tid; i < 16 * 520; i += 512) Xa[i] = 0;
    const int lane = tid & 63, w = tid >> 6;  // 8 waves, wave = 16-col tile
    const int l15 = lane & 15, l4 = lane >> 4;
    float c_reg = 0.f;
    if (tid < 256) {
      int b = tid >> 5, jj = tid & 31;
      c_reg = decc0[(size_t)(8 * g + b) * 256 + 32 * s + jj];
    }
    __syncthreads();
    for (int t = 0; t < 63; t++) {
      if (t > 0) {
        if (tid < 8)
          while (ld_u32(&zfl[tid * 32]) < (uint)t) __builtin_amdgcn_s_sleep(2);
        else if (tid >= 64 && tid < 80)
          while (ld_u32(&afl[(tid - 64) * 32]) < (uint)t) __builtin_amdgcn_s_sleep(2);
        asm volatile("" ::: "memory");
        __syncthreads();
      }
      const uint* Xr = Xd_u32 + (size_t)(t & 1) * 16384;
      for (int i = tid; i < 8 * 256; i += 512) {
        int row = i >> 8, colu = i & 255;
        uint v = ld_u32(Xr + (size_t)(8 * g + row) * 256 + colu);
        *(uint*)&Xa[row * 520 + colu * 2] = v;
      }
      __syncthreads();
      f32x4 accv = (f32x4){0.f, 0.f, 0.f, 0.f};
      for (int kk = 0; kk < 16; kk++) {
        bf16x8 af = *(const bf16x8*)&Xa[l15 * 520 + kk * 32 + l4 * 8];
        bf16x8 bf = *(const bf16x8*)&Wl[(w * 16 + l15) * 520 + kk * 32 + l4 * 8];
        accv = __builtin_amdgcn_mfma_f32_16x16x32_bf16(af, bf, accv, 0, 0, 0);
      }
      if (l4 < 2) {
        #pragma unroll
        for (int r = 0; r < 4; r++) {
          int b = l4 * 4 + r;
          zslds[b * 128 + w * 16 + l15] = accv[r];
        }
      }
      __syncthreads();
      if (tid < 256) {  // LSTM gates + h for this slice (c in register)
        int b = tid >> 5, jj = tid & 31;
        int gb = 8 * g + b;
        const float* yw = YW + (size_t)(t * 64 + gb) * 1024 + 32 * s + jj;
        float zi = zslds[b * 128 + jj] + yw[0];
        float zf = zslds[b * 128 + 32 + jj] + yw[256];
        float zg = zslds[b * 128 + 64 + jj] + yw[512];
        float zo = zslds[b * 128 + 96 + jj] + yw[768];
        float c = sigf(zf) * c_reg + sigf(zi) * tanhfast(zg);
        c_reg = c;
        hsb[b * 32 + jj] = sigf(zo) * tanhfast(c);
      }
      __syncthreads();
      if (tid < 128) {  // packed uncached h-slice store
        int b = tid >> 4, p = tid & 15;
        uint v = (uint)f2bu(hsb[b * 32 + 2 * p]) | ((uint)f2bu(hsb[b * 32 + 2 * p + 1]) << 16);
        st_u32(Xd_u32 + (size_t)((t & 1) ^ 1) * 16384 + (size_t)(8 * g + b) * 256 + 16 * s + p, v);
      }
      __syncthreads();  // drains vmcnt
      if (tid == 0) st_u32(&zfl[s * 32], (uint)(t + 1));
    }
  } else {
    // ------------- attention block: b = 8g+lb, O-half jh ----------------------
    const int lb = (kb - 8) >> 1, jh = (kb - 8) & 1;
    const int b = 8 * g + lb;
    ushort* ep = (ushort*)smem;                    // [64][264] = 33792 B
    ushort* eh = (ushort*)(smem + 33792);          // [64][520] = 66560 B
    float* hn = (float*)(smem + 100352);           // 256 f
    float* xcomb = (float*)(smem + 101376);        // 768 f
    float* e_l = (float*)(smem + 104448);          // 64
    float* alpha_l = (float*)(smem + 104704);      // 64
    float* op_l = (float*)(smem + 104960);         // [4][128] f
    float* Ost = (float*)(smem + 107008);          // 128 f
    for (int i = tid; i < 64 * 256; i += 512) {
      int s2 = i >> 8, k2 = i & 255;
      ep[s2 * 264 + k2] = ((const ushort*)encproj_bf)[(size_t)(b * 64 + s2) * 256 + k2];
    }
    for (int i = tid; i < 64 * 512; i += 512) {
      int s2 = i >> 9, d = i & 511;
      ushort v = (d < 256) ? ((const ushort*)fwd_bf)[(size_t)(s2 * 64 + b) * 256 + d]
                           : ((const ushort*)bwd_bf)[(size_t)(s2 * 64 + b) * 256 + d - 256];
      eh[s2 * 520 + d] = v;
    }
    __syncthreads();
    for (int t = 0; t < 63; t++) {
      if (tid < 8)
        while (ld_u32(&zfl[tid * 32]) < (uint)(t + 1)) __builtin_amdgcn_s_sleep(2);
      asm volatile("" ::: "memory");
      __syncthreads();
      if (tid < 128) {  // stage h(t+1) (uncached, packed)
        uint v = ld_u32(Xd_u32 + (size_t)((t & 1) ^ 1) * 16384 + (size_t)b * 256 + tid);
        hn[2 * tid] = bflo(v);
        hn[2 * tid + 1] = bfhi(v);
      }
      __syncthreads();
      {  // e[s]
        int s2 = tid >> 3, q8 = tid & 7;
        const ushort* pr = ep + s2 * 264 + q8 * 32;
        const float* hq = hn + q8 * 32;
        float a = 0.f;
        #pragma unroll 8
        for (int kk = 0; kk < 32; kk += 2) {
          uint wv = *(const uint*)(pr + kk);
          a += bflo(wv) * hq[kk] + bfhi(wv) * hq[kk + 1];
        }
        a += __shfl_xor(a, 1);
        a += __shfl_xor(a, 2);
        a += __shfl_xor(a, 4);
        if (q8 == 0) e_l[s2] = a;
      }
      __syncthreads();
      if (tid < 64) {
        float e = e_l[tid];
        float mx = e;
        #pragma unroll
        for (int o = 32; o > 0; o >>= 1) mx = fmaxf(mx, __shfl_xor(mx, o));
        float p = __expf(e - mx);
        float ss = p;
        #pragma unroll
        for (int o = 32; o > 0; o >>= 1) ss += __shfl_xor(ss, o);
        alpha_l[tid] = p / ss;
      }
      __syncthreads();
      {  // a_t[d]
        float a = 0.f;
        const ushort* col = eh + tid;
        #pragma unroll 8
        for (int s2 = 0; s2 < 64; s2++)
          a += alpha_l[s2] * __uint_as_float(((uint)col[s2 * 520]) << 16);
        xcomb[tid] = a;
        if (tid < 256) xcomb[512 + tid] = hn[tid];
      }
      __syncthreads();
      {  // O-half = tanh(xcomb . Wcomb^T), stream Wcq half (L2-resident)
        int jl = tid & 127, kq = tid >> 7;
        int j = jh * 128 + jl;
        const uint2* wp = Wcq + (size_t)(kq * 48) * 256 + j;
        const float4* x4 = (const float4*)xcomb + kq * 48;
        float a = 0.f;
        #pragma unroll 6
        for (int ii = 0; ii < 48; ii++) {
          uint2 wv = wp[(size_t)ii * 256];
          float4 xv = x4[ii];
          a += bflo(wv.x) * xv.x + bfhi(wv.x) * xv.y + bflo(wv.y) * xv.z + bfhi(wv.y) * xv.w;
        }
        op_l[kq * 128 + jl] = a;
      }
      __syncthreads();
      if (tid < 128) {
        float sum = op_l[tid] + op_l[128 + tid] + op_l[256 + tid] + op_l[384 + tid];
        float O = tanhfast(sum);
        Ost[tid] = O;
        ((ushort*)outs_bf)[(size_t)(t * 64 + b) * 256 + jh * 128 + tid] = f2bu(O);
      }
      __syncthreads();
      if (tid < 64) {  // packed uncached O store
        uint v = (uint)f2bu(Ost[2 * tid]) | ((uint)f2bu(Ost[2 * tid + 1]) << 16);
        st_u32(Xd_u32 + (size_t)((t & 1) ^ 1) * 16384 + (size_t)b * 256 + 128 + jh * 64 + tid, v);
      }
      __syncthreads();  // drains vmcnt
      if (tid == 0) st_u32(&afl[(lb * 2 + jh) * 32], (uint)(t + 1));
    }
  }
}

// ---------------- final reduce ------------------------------------------------
__global__ __launch_bounds__(256) void k_final(
    const float* __restrict__ part_max, const float* __restrict__ part_sum,
    const float* __restrict__ gold, const int* __restrict__ tgt,
    float* __restrict__ out) {
  int b = blockIdx.x, tid = threadIdx.x;
  int tq = tid >> 2, q = tid & 3;
  __shared__ float lm[64][4], ls[64][4];
  __shared__ float red[64];
  if (tq < T - 1) {
    int n = tq * B + b;
    float m = -__builtin_inff(), s = 0;
    for (int i = q; i < NCHUNK; i += 4) {
      float pmv = part_max[(size_t)i * NROW + n];
      float psv = part_sum[(size_t)i * NROW + n];
      float M2 = fmaxf(m, pmv);
      s = s * __expf(m - M2) + psv * __expf(pmv - M2);
      m = M2;
    }
    lm[tq][q] = m;
    ls[tq][q] = s;
  }
  __syncthreads();
  if (tid < T - 1) {
    float M = fmaxf(fmaxf(lm[tid][0], lm[tid][1]), fmaxf(lm[tid][2], lm[tid][3]));
    float Ss = ls[tid][0] * __expf(lm[tid][0] - M) + ls[tid][1] * __expf(lm[tid][1] - M) +
               ls[tid][2] * __expf(lm[tid][2] - M) + ls[tid][3] * __expf(lm[tid][3] - M);
    float lse = M + logf(Ss);
    int g = tgt[(tid + 1) * B + b];
    red[tid] = (g != 0) ? (gold[tid * B + b] - lse) : 0.f;
  }
  if (tid == T - 1) red[T - 1] = 0.f;
  __syncthreads();
  if (tid == 0) {
    float s = 0;
    for (int i = 0; i < T - 1; i++) s += red[i];
    out[b] = s;
  }
}

extern "C" void kernel_launch(void* const* d_in, const int* in_sizes, int n_in,
                              void* d_out, int out_size, void* d_ws, size_t ws_size,
                              hipStream_t stream) {
  (void)in_sizes; (void)n_in; (void)out_size; (void)ws_size;
  const int*   src   = (const int*)  d_in[0];
  const int*   tgt   = (const int*)  d_in[1];
  const float* semb  = (const float*)d_in[2];
  const float* temb  = (const float*)d_in[3];
  const float* WihF  = (const float*)d_in[4];
  const float* WhhF  = (const float*)d_in[5];
  const float* bF    = (const float*)d_in[6];
  const float* WihB  = (const float*)d_in[7];
  const float* WhhB  = (const float*)d_in[8];
  const float* bB    = (const float*)d_in[9];
  const float* dWih  = (const float*)d_in[10];
  const float* dWhh  = (const float*)d_in[11];
  const float* db    = (const float*)d_in[12];
  const float* Wh    = (const float*)d_in[13];
  const float* Wc    = (const float*)d_in[14];
  const float* Watt  = (const float*)d_in[15];
  const float* Wcomb = (const float*)d_in[16];
  const float* Wv    = (const float*)d_in[17];
  float* out = (float*)d_out;

  char* wp = (char*)d_ws;
  auto alloc = [&](size_t bytes) -> char* {
    char* p = wp;
    wp += (bytes + 255) & ~(size_t)255;
    return p;
  };
  float* XwF  = (float*)alloc((size_t)S * B * H4 * 4);
  float* XwB  = (float*)alloc((size_t)S * B * H4 * 4);
  float* YW   = (float*)alloc((size_t)(T - 1) * B * H4 * 4);
  __hip_bfloat16* fwd_bf     = (__hip_bfloat16*)alloc((size_t)S * B * H * 2);
  __hip_bfloat16* bwd_bf     = (__hip_bfloat16*)alloc((size_t)S * B * H * 2);
  __hip_bfloat16* encproj_bf = (__hip_bfloat16*)alloc((size_t)B * S * H * 2);
  __hip_bfloat16* Ag         = (__hip_bfloat16*)alloc((size_t)S * B * E * 2);
  __hip_bfloat16* Yg         = (__hip_bfloat16*)alloc((size_t)(T - 1) * B * E * 2);
  __hip_bfloat16* WihF_bf    = (__hip_bfloat16*)alloc((size_t)H4 * E * 2);
  __hip_bfloat16* WihB_bf    = (__hip_bfloat16*)alloc((size_t)H4 * E * 2);
  __hip_bfloat16* dWih_bf    = (__hip_bfloat16*)alloc((size_t)H4 * E * 2);
  __hip_bfloat16* Wv_bf      = (__hip_bfloat16*)alloc((size_t)V * H * 2);
  __hip_bfloat16* Watt_bf    = (__hip_bfloat16*)alloc((size_t)H * 512 * 2);
  __hip_bfloat16* outs_bf    = (__hip_bfloat16*)alloc((size_t)NROW * H * 2);
  uint2* Wcq = (uint2*)alloc((size_t)192 * 256 * 8);
  float* part_max = (float*)alloc((size_t)NCHUNK * NROW * 4);
  float* part_sum = (float*)alloc((size_t)NCHUNK * NROW * 4);
  float* gold     = (float*)alloc((size_t)NROW * 4);
  float* Cfin  = (float*)alloc((size_t)2 * B * H * 4);
  float* decc0 = (float*)alloc((size_t)B * H * 4);
  __hip_bfloat16* Xenc = (__hip_bfloat16*)alloc((size_t)2 * 2 * B * H * 2);  // [par][dir][b][j]
  uint* Xdec = (uint*)alloc((size_t)2 * B * 256 * 4);                        // [par][b][h|O] packed
  // state: flags, zeroed every call
  char* stateBase = wp;
  uint* eflags = (uint*)alloc(16 * 8 * 32 * 4);
  uint* zflags = (uint*)alloc(8 * 8 * 32 * 4);
  uint* aflags = (uint*)alloc(8 * 16 * 32 * 4);
  size_t stateBytes = (size_t)(wp - stateBase);
  hipMemsetAsync(stateBase, 0, stateBytes, stream);
  hipMemsetAsync(Xenc, 0, (size_t)2 * 2 * B * H * 2, stream);

  // converts + gathers + packs
  hipLaunchKernelGGL(k_cvt_bf16, dim3((H4 * E + 255) / 256), dim3(256), 0, stream,
                     WihF, WihF_bf, H4 * E);
  hipLaunchKernelGGL(k_cvt_bf16, dim3((H4 * E + 255) / 256), dim3(256), 0, stream,
                     WihB, WihB_bf, H4 * E);
  hipLaunchKernelGGL(k_cvt_slice, dim3(H4), dim3(256), 0, stream, dWih, dWih_bf);
  hipLaunchKernelGGL(k_cvt_bf16, dim3((V * H + 255) / 256), dim3(256), 0, stream,
                     Wv, Wv_bf, V * H);
  hipLaunchKernelGGL(k_cvt_bf16, dim3((H * 512 + 255) / 256), dim3(256), 0, stream,
                     Watt, Watt_bf, H * 512);
  hipLaunchKernelGGL(k_gather, dim3(S * B), dim3(256), 0, stream, src, semb, Ag);
  hipLaunchKernelGGL(k_gather, dim3((T - 1) * B), dim3(256), 0, stream, tgt, temb, Yg);
  hipLaunchKernelGGL(k_pack4, dim3(192 * 256 / 256), dim3(256), 0, stream,
                     Wcomb, Wcq, 192 * 256, 8, 768, 0);

  // input GEMMs (MFMA)
  hipLaunchKernelGGL(k_gemm_bias, dim3(H4 / 64, S * B / 64), dim3(256), 0, stream,
                     Ag, WihF_bf, bF, XwF, H4);
  hipLaunchKernelGGL(k_gemm_bias, dim3(H4 / 64, S * B / 64), dim3(256), 0, stream,
                     Ag, WihB_bf, bB, XwB, H4);
  hipLaunchKernelGGL(k_gemm_bias, dim3(H4 / 64, (T - 1) * B / 64), dim3(256), 0, stream,
                     Yg, dWih_bf, db, YW, H4);

  // encoder: 128 blocks, XCD-local octets, uncached exchange
  hipLaunchKernelGGL(k_enc4, dim3(128), dim3(256), 0, stream,
                     XwF, XwB, WhhF, WhhB, (uint*)Xenc, fwd_bf, bwd_bf, Cfin, eflags);
  hipLaunchKernelGGL(k_dec_init3, dim3(B), dim3(256), 0, stream,
                     Xenc, Cfin, Wh, Wc, Xdec, decc0);
  hipLaunchKernelGGL(k_encproj_mfma, dim3(4, 64), dim3(256), 0, stream,
                     fwd_bf, bwd_bf, Watt_bf, encproj_bf);

  // decoder: 192 blocks (64 z + 128 attention), z-blocks own gates + h
  hipLaunchKernelGGL(k_dec5, dim3(192), dim3(512), 0, stream,
                     YW, dWih, dWhh, Wcq, encproj_bf, fwd_bf, bwd_bf,
                     decc0, Xdec, outs_bf, zflags, aflags);

  // vocab projection (B-stationary) + final reduce
  hipLaunchKernelGGL(k_vocab2, dim3(NCHUNK), dim3(256), 0, stream,
                     outs_bf, Wv_bf, tgt, part_max, part_sum, gold);
  hipLaunchKernelGGL(k_final, dim3(B), dim3(256), 0, stream,
                     part_max, part_sum, gold, tgt, out);
}

// Round 11
// 1208.857 us; speedup vs baseline: 1.0362x; 1.0362x over previous
//
#include <hip/hip_runtime.h>
#include <hip/hip_bf16.h>

static constexpr int S = 64, T = 64, B = 64, E = 256, H = 256, V = 32000;
static constexpr int H4 = 4 * H;          // 1024
static constexpr int NCHUNK = 500;        // V / 64
static constexpr int NROW = (T - 1) * B;  // 4032
static constexpr int LDP = 264;           // LDS row stride (bf16) for MFMA staging tiles

typedef short bf16x8 __attribute__((ext_vector_type(8)));
typedef float f32x4 __attribute__((ext_vector_type(4)));
typedef unsigned long long ull;

__device__ __forceinline__ float sigf(float x) { return 1.0f / (1.0f + __expf(-x)); }
__device__ __forceinline__ float tanhfast(float x) { return 1.0f - 2.0f / (__expf(2.0f * x) + 1.0f); }
__device__ __forceinline__ float bflo(uint w) { return __uint_as_float(w << 16); }
__device__ __forceinline__ float bfhi(uint w) { return __uint_as_float(w & 0xffff0000u); }
__device__ __forceinline__ ushort f2bu(float x) {
  return __bfloat16_as_ushort(__float2bfloat16(x));
}

// ---- relaxed agent-scope (cache-bypassing, NO wbl2/inv) primitives ----
__device__ __forceinline__ void st_u32(uint* p, uint v) {
  __hip_atomic_store(p, v, __ATOMIC_RELAXED, __HIP_MEMORY_SCOPE_AGENT);
}
__device__ __forceinline__ uint ld_u32(const uint* p) {
  return __hip_atomic_load(p, __ATOMIC_RELAXED, __HIP_MEMORY_SCOPE_AGENT);
}
// NOTE: data stores are uncached; the __syncthreads() before a flag post drains
// each wave's vmcnt (compiler-inserted s_waitcnt before s_barrier) so data is at
// the coherence point before the flag becomes visible.

// ---------------- small utility kernels ----------------
__global__ __launch_bounds__(256) void k_cvt_bf16(const float* __restrict__ src,
                                                  __hip_bfloat16* __restrict__ dst, int n) {
  int i = blockIdx.x * 256 + threadIdx.x;
  if (i < n) dst[i] = __float2bfloat16(src[i]);
}

__global__ __launch_bounds__(256) void k_cvt_slice(const float* __restrict__ src,
                                                   __hip_bfloat16* __restrict__ dst) {
  int n = blockIdx.x, tid = threadIdx.x;
  dst[n * 256 + tid] = __float2bfloat16(src[n * 512 + tid]);
}

__global__ __launch_bounds__(256) void k_gather(const int* __restrict__ idx,
                                                const float* __restrict__ emb,
                                                __hip_bfloat16* __restrict__ dst) {
  int r = blockIdx.x, tid = threadIdx.x;
  dst[r * 256 + tid] = __float2bfloat16(emb[idx[r] * E + tid]);
}

// quad-k pack: dst[i][j] = bf16 src[j][4i..4i+3]  (uint2 [K/4][J])
__global__ __launch_bounds__(256) void k_pack4(const float* __restrict__ src,
                                               uint2* __restrict__ dst,
                                               int total, int jshift, int ld, int off) {
  int idx = blockIdx.x * 256 + threadIdx.x;
  if (idx >= total) return;
  int J = 1 << jshift;
  int i = idx >> jshift, j = idx & (J - 1);
  const float* s = src + (size_t)j * ld + off + 4 * i;
  float4 v = *(const float4*)s;
  uint2 o;
  o.x = (uint)f2bu(v.x) | ((uint)f2bu(v.y) << 16);
  o.y = (uint)f2bu(v.z) | ((uint)f2bu(v.w) << 16);
  dst[(size_t)i * J + j] = o;
}

// ============ shared MFMA 64x64 tile core (K=256, bf16 in, f32 acc) ===========
#define MFMA_TILE_BODY(Abase, Wbase, rb, cb)                                     \
  const int tid = threadIdx.x;                                                   \
  const int lane = tid & 63, wid = tid >> 6;                                     \
  const int wr = wid >> 1, wc = wid & 1;                                         \
  const int l15 = lane & 15, l4 = lane >> 4;                                     \
  for (int it = 0; it < 8; it++) {                                               \
    int c = it * 256 + tid;                                                      \
    int row = c >> 5, off = (c & 31) * 8;                                        \
    *(uint4*)&Asl[row * LDP + off] =                                             \
        *(const uint4*)((Abase) + (size_t)((rb) + row) * 256 + off);             \
    *(uint4*)&Bsl[row * LDP + off] =                                             \
        *(const uint4*)((Wbase) + (size_t)((cb) + row) * 256 + off);             \
  }                                                                              \
  __syncthreads();                                                               \
  f32x4 acc[2][2];                                                               \
  for (int m = 0; m < 2; m++)                                                    \
    for (int n = 0; n < 2; n++) acc[m][n] = (f32x4){0.f, 0.f, 0.f, 0.f};         \
  for (int kk = 0; kk < 8; kk++) {                                               \
    int ko = kk * 32 + l4 * 8;                                                   \
    bf16x8 a0 = *(const bf16x8*)&Asl[(wr * 32 + l15) * LDP + ko];                \
    bf16x8 a1 = *(const bf16x8*)&Asl[(wr * 32 + 16 + l15) * LDP + ko];           \
    bf16x8 b0 = *(const bf16x8*)&Bsl[(wc * 32 + l15) * LDP + ko];                \
    bf16x8 b1 = *(const bf16x8*)&Bsl[(wc * 32 + 16 + l15) * LDP + ko];           \
    acc[0][0] = __builtin_amdgcn_mfma_f32_16x16x32_bf16(a0, b0, acc[0][0], 0, 0, 0); \
    acc[0][1] = __builtin_amdgcn_mfma_f32_16x16x32_bf16(a0, b1, acc[0][1], 0, 0, 0); \
    acc[1][0] = __builtin_amdgcn_mfma_f32_16x16x32_bf16(a1, b0, acc[1][0], 0, 0, 0); \
    acc[1][1] = __builtin_amdgcn_mfma_f32_16x16x32_bf16(a1, b1, acc[1][1], 0, 0, 0); \
  }

// ---------------- generic GEMM + bias -----------------------------------------
__global__ __launch_bounds__(256) void k_gemm_bias(
    const __hip_bfloat16* __restrict__ A, const __hip_bfloat16* __restrict__ W,
    const float* __restrict__ bias, float* __restrict__ C, int ldc) {
  __shared__ __align__(16) ushort Asl[64 * LDP];
  __shared__ __align__(16) ushort Bsl[64 * LDP];
  const int cb = blockIdx.x * 64, rb = blockIdx.y * 64;
  MFMA_TILE_BODY((const ushort*)A, (const ushort*)W, rb, cb)
  #pragma unroll
  for (int m = 0; m < 2; m++)
    #pragma unroll
    for (int n = 0; n < 2; n++) {
      int col = cb + wc * 32 + n * 16 + l15;
      float bv = bias[col];
      #pragma unroll
      for (int r = 0; r < 4; r++) {
        int row = rb + wr * 32 + m * 16 + l4 * 4 + r;
        C[(size_t)row * ldc + col] = acc[m][n][r] + bv;
      }
    }
}

// ---------------- enc_proj as MFMA GEMM: 4096x256, K=512 ----------------------
__global__ __launch_bounds__(256) void k_encproj_mfma(
    const __hip_bfloat16* __restrict__ fwd_bf, const __hip_bfloat16* __restrict__ bwd_bf,
    const __hip_bfloat16* __restrict__ Watt_bf, __hip_bfloat16* __restrict__ encproj_bf) {
  __shared__ __align__(16) ushort Asl[64 * LDP];
  __shared__ __align__(16) ushort Bsl[64 * LDP];
  const int cb = blockIdx.x * 64, rb = blockIdx.y * 64;
  const int tid = threadIdx.x;
  const int lane = tid & 63, wid = tid >> 6;
  const int wr = wid >> 1, wc = wid & 1;
  const int l15 = lane & 15, l4 = lane >> 4;
  f32x4 acc[2][2];
  #pragma unroll
  for (int m = 0; m < 2; m++)
    #pragma unroll
    for (int n = 0; n < 2; n++) acc[m][n] = (f32x4){0.f, 0.f, 0.f, 0.f};
  for (int kt = 0; kt < 2; kt++) {
    if (kt) __syncthreads();
    for (int it = 0; it < 8; it++) {
      int c = it * 256 + tid;
      int row = c >> 5, off = (c & 31) * 8;
      int r = rb + row, s = r >> 6, bb = r & 63;
      const ushort* arow = (kt == 0)
          ? (const ushort*)fwd_bf + (size_t)(s * 64 + bb) * 256
          : (const ushort*)bwd_bf + (size_t)(s * 64 + bb) * 256;
      *(uint4*)&Asl[row * LDP + off] = *(const uint4*)(arow + off);
      *(uint4*)&Bsl[row * LDP + off] =
          *(const uint4*)((const ushort*)Watt_bf + (size_t)(cb + row) * 512 + kt * 256 + off);
    }
    __syncthreads();
    for (int kk = 0; kk < 8; kk++) {
      int ko = kk * 32 + l4 * 8;
      bf16x8 a0 = *(const bf16x8*)&Asl[(wr * 32 + l15) * LDP + ko];
      bf16x8 a1 = *(const bf16x8*)&Asl[(wr * 32 + 16 + l15) * LDP + ko];
      bf16x8 b0 = *(const bf16x8*)&Bsl[(wc * 32 + l15) * LDP + ko];
      bf16x8 b1 = *(const bf16x8*)&Bsl[(wc * 32 + 16 + l15) * LDP + ko];
      acc[0][0] = __builtin_amdgcn_mfma_f32_16x16x32_bf16(a0, b0, acc[0][0], 0, 0, 0);
      acc[0][1] = __builtin_amdgcn_mfma_f32_16x16x32_bf16(a0, b1, acc[0][1], 0, 0, 0);
      acc[1][0] = __builtin_amdgcn_mfma_f32_16x16x32_bf16(a1, b0, acc[1][0], 0, 0, 0);
      acc[1][1] = __builtin_amdgcn_mfma_f32_16x16x32_bf16(a1, b1, acc[1][1], 0, 0, 0);
    }
  }
  #pragma unroll
  for (int m = 0; m < 2; m++)
    #pragma unroll
    for (int n = 0; n < 2; n++) {
      int col = cb + wc * 32 + n * 16 + l15;
      #pragma unroll
      for (int r = 0; r < 4; r++) {
        int row = rb + wr * 32 + m * 16 + l4 * 4 + r;
        int s = row >> 6, bb = row & 63;
        ((ushort*)encproj_bf)[(size_t)(bb * 64 + s) * 256 + col] = f2bu(acc[m][n][r]);
      }
    }
}

// ---------------- vocab: B-stationary, loop over t ----------------------------
__global__ __launch_bounds__(256) void k_vocab2(
    const __hip_bfloat16* __restrict__ outs_bf, const __hip_bfloat16* __restrict__ Wv,
    const int* __restrict__ tgt, float* __restrict__ part_max,
    float* __restrict__ part_sum, float* __restrict__ gold) {
  __shared__ __align__(16) ushort Asl[64 * LDP];
  __shared__ __align__(16) ushort Bsl[64 * LDP];
  __shared__ int goldcol[64];
  __shared__ float pm[64][2], ps[64][2];
  const int vb = blockIdx.x;
  const int tid = threadIdx.x;
  const int lane = tid & 63, wid = tid >> 6;
  const int wr = wid >> 1, wc = wid & 1;
  const int l15 = lane & 15, l4 = lane >> 4;
  for (int it = 0; it < 8; it++) {
    int c = it * 256 + tid;
    int row = c >> 5, off = (c & 31) * 8;
    *(uint4*)&Bsl[row * LDP + off] =
        *(const uint4*)((const ushort*)Wv + (size_t)(vb * 64 + row) * 256 + off);
  }
  for (int t = 0; t < T - 1; t++) {
    __syncthreads();
    for (int it = 0; it < 8; it++) {
      int c = it * 256 + tid;
      int row = c >> 5, off = (c & 31) * 8;
      *(uint4*)&Asl[row * LDP + off] =
          *(const uint4*)((const ushort*)outs_bf + (size_t)(t * 64 + row) * 256 + off);
    }
    if (tid < 64) goldcol[tid] = tgt[(t + 1) * B + tid];
    __syncthreads();
    f32x4 acc[2][2];
    #pragma unroll
    for (int m = 0; m < 2; m++)
      #pragma unroll
      for (int n = 0; n < 2; n++) acc[m][n] = (f32x4){0.f, 0.f, 0.f, 0.f};
    for (int kk = 0; kk < 8; kk++) {
      int ko = kk * 32 + l4 * 8;
      bf16x8 a0 = *(const bf16x8*)&Asl[(wr * 32 + l15) * LDP + ko];
      bf16x8 a1 = *(const bf16x8*)&Asl[(wr * 32 + 16 + l15) * LDP + ko];
      bf16x8 b0 = *(const bf16x8*)&Bsl[(wc * 32 + l15) * LDP + ko];
      bf16x8 b1 = *(const bf16x8*)&Bsl[(wc * 32 + 16 + l15) * LDP + ko];
      acc[0][0] = __builtin_amdgcn_mfma_f32_16x16x32_bf16(a0, b0, acc[0][0], 0, 0, 0);
      acc[0][1] = __builtin_amdgcn_mfma_f32_16x16x32_bf16(a0, b1, acc[0][1], 0, 0, 0);
      acc[1][0] = __builtin_amdgcn_mfma_f32_16x16x32_bf16(a1, b0, acc[1][0], 0, 0, 0);
      acc[1][1] = __builtin_amdgcn_mfma_f32_16x16x32_bf16(a1, b1, acc[1][1], 0, 0, 0);
    }
    #pragma unroll
    for (int m = 0; m < 2; m++) {
      #pragma unroll
      for (int r = 0; r < 4; r++) {
        int row_local = wr * 32 + m * 16 + l4 * 4 + r;
        int gc = goldcol[row_local];
        #pragma unroll
        for (int n = 0; n < 2; n++) {
          int col = vb * 64 + wc * 32 + n * 16 + l15;
          if (col == gc) gold[t * 64 + row_local] = acc[m][n][r];
        }
        float v = fmaxf(acc[m][0][r], acc[m][1][r]);
        #pragma unroll
        for (int o = 1; o < 16; o <<= 1) v = fmaxf(v, __shfl_xor(v, o));
        float e = __expf(acc[m][0][r] - v) + __expf(acc[m][1][r] - v);
        #pragma unroll
        for (int o = 1; o < 16; o <<= 1) e += __shfl_xor(e, o);
        if (l15 == 0) { pm[row_local][wc] = v; ps[row_local][wc] = e; }
      }
    }
    __syncthreads();
    if (tid < 64) {
      float m0 = pm[tid][0], m1 = pm[tid][1];
      float M = fmaxf(m0, m1);
      float Ss = ps[tid][0] * __expf(m0 - M) + ps[tid][1] * __expf(m1 - M);
      part_max[(size_t)vb * NROW + t * 64 + tid] = M;
      part_sum[(size_t)vb * NROW + t * 64 + tid] = Ss;
    }
  }
}

// ---------------- encoder: 128 blocks, XCD-local octets, uncached exchange ----
__global__ __launch_bounds__(256) void k_enc4(
    const float* __restrict__ XwF, const float* __restrict__ XwB,
    const float* __restrict__ WhhF, const float* __restrict__ WhhB,
    uint* __restrict__ Xenc_u32,
    __hip_bfloat16* __restrict__ fwd_bf, __hip_bfloat16* __restrict__ bwd_bf,
    float* __restrict__ Cfin, uint* __restrict__ eflags) {
  __shared__ __align__(16) ushort Wl[128 * 264];  // 67584 B
  __shared__ __align__(16) ushort Xa[16 * 264];   // 8448 B
  __shared__ float zz[4][8][33];
  __shared__ float hsb[8][32];
  const int id = blockIdx.x;
  const int g = id & 7, kb = id >> 3;
  const int dir = kb >> 3, s = kb & 7;
  const int tid = threadIdx.x;
  const float* Whh = dir ? WhhB : WhhF;
  const float* Xw = dir ? XwB : XwF;
  uint* fl = eflags + (size_t)(g * 2 + dir) * 8 * 32;
  for (int i = tid; i < 128 * 256; i += 256) {
    int c = i >> 8, k2 = i & 255;
    int gate = c >> 5, jj = c & 31;
    Wl[c * 264 + k2] = f2bu(Whh[(size_t)(gate * 256 + s * 32 + jj) * 256 + k2]);
  }
  for (int i = tid; i < 16 * 264; i += 256) Xa[i] = 0;
  const int lane = tid & 63, w = tid >> 6;   // wave = gate
  const int l15 = lane & 15, l4 = lane >> 4;
  const int tb = tid >> 5, tjj = tid & 31;
  float c_reg = 0.f;
  __syncthreads();
  for (int st = 0; st < 64; st++) {
    const int ts = dir ? 63 - st : st;
    const int par = st & 1;
    const uint* Xr = Xenc_u32 + (size_t)(par * 2 + dir) * 8192;
    uint* Xo = Xenc_u32 + (size_t)((par ^ 1) * 2 + dir) * 8192;
    for (int i = tid; i < 8 * 128; i += 256) {
      int row = i >> 7, colu = i & 127;
      uint v = ld_u32(Xr + (size_t)(8 * g + row) * 128 + colu);
      *(uint*)&Xa[row * 264 + colu * 2] = v;
    }
    __syncthreads();
    f32x4 a0v = (f32x4){0.f, 0.f, 0.f, 0.f}, a1v = (f32x4){0.f, 0.f, 0.f, 0.f};
    for (int kk = 0; kk < 8; kk++) {
      bf16x8 af = *(const bf16x8*)&Xa[l15 * 264 + kk * 32 + l4 * 8];
      bf16x8 b0 = *(const bf16x8*)&Wl[((2 * w) * 16 + l15) * 264 + kk * 32 + l4 * 8];
      bf16x8 b1 = *(const bf16x8*)&Wl[((2 * w + 1) * 16 + l15) * 264 + kk * 32 + l4 * 8];
      a0v = __builtin_amdgcn_mfma_f32_16x16x32_bf16(af, b0, a0v, 0, 0, 0);
      a1v = __builtin_amdgcn_mfma_f32_16x16x32_bf16(af, b1, a1v, 0, 0, 0);
    }
    if (l4 < 2) {
      #pragma unroll
      for (int r = 0; r < 4; r++) {
        int b = l4 * 4 + r;
        zz[w][b][l15] = a0v[r];
        zz[w][b][16 + l15] = a1v[r];
      }
    }
    __syncthreads();
    {
      int gb = 8 * g + tb, j = 32 * s + tjj;
      const float* xw = Xw + (size_t)(ts * 64 + gb) * 1024;
      float zi = zz[0][tb][tjj] + xw[j];
      float zf = zz[1][tb][tjj] + xw[256 + j];
      float zg = zz[2][tb][tjj] + xw[512 + j];
      float zo = zz[3][tb][tjj] + xw[768 + j];
      float c = sigf(zf) * c_reg + sigf(zi) * tanhfast(zg);
      c_reg = c;
      float h = sigf(zo) * tanhfast(c);
      hsb[tb][tjj] = h;
      ushort hb = f2bu(h);
      if (dir == 0) ((ushort*)fwd_bf)[(size_t)(st * 64 + gb) * 256 + j] = hb;
      else          ((ushort*)bwd_bf)[(size_t)((63 - st) * 64 + gb) * 256 + j] = hb;
    }
    __syncthreads();
    if (tid < 128) {  // packed uncached h store (2 bf16 per uint)
      int tb2 = tid >> 4, p = tid & 15;
      uint v = (uint)f2bu(hsb[tb2][2 * p]) | ((uint)f2bu(hsb[tb2][2 * p + 1]) << 16);
      st_u32(Xo + (size_t)(8 * g + tb2) * 128 + 16 * s + p, v);
    }
    __syncthreads();  // drains vmcnt -> uncached stores at coherence point
    if (tid == 0) st_u32(&fl[s * 32], (uint)(st + 1));
    if (tid < 8)
      while (ld_u32(&fl[tid * 32]) < (uint)(st + 1)) __builtin_amdgcn_s_sleep(2);
    asm volatile("" ::: "memory");
    __syncthreads();
  }
  Cfin[(size_t)(dir * 64 + 8 * g + tb) * 256 + 32 * s + tjj] = c_reg;
}

// ---------------- decoder init: dec_h/dec_c + packed Xd[0] --------------------
__global__ __launch_bounds__(256) void k_dec_init3(
    const __hip_bfloat16* __restrict__ Xenc, const float* __restrict__ Cfin,
    const float* __restrict__ Wh, const float* __restrict__ Wc,
    uint* __restrict__ Xd_u32, float* __restrict__ decc0) {
  int b = blockIdx.x, tid = threadIdx.x;
  __shared__ __align__(16) float ch[512], cc[512];
  __shared__ float hh[256];
  ch[tid]       = __bfloat162float(Xenc[(size_t)(0 * 64 + b) * 256 + tid]);
  ch[256 + tid] = __bfloat162float(Xenc[(size_t)(1 * 64 + b) * 256 + tid]);
  cc[tid]       = Cfin[(size_t)(0 * 64 + b) * 256 + tid];
  cc[256 + tid] = Cfin[(size_t)(1 * 64 + b) * 256 + tid];
  __syncthreads();
  const float* wh = Wh + tid * 512;
  const float* wc = Wc + tid * 512;
  float ah = 0, ac = 0;
  for (int k = 0; k < 512; k += 4) {
    float4 hv = *(const float4*)&ch[k];
    float4 cv = *(const float4*)&cc[k];
    float4 w1 = *(const float4*)&wh[k];
    float4 w2 = *(const float4*)&wc[k];
    ah += hv.x * w1.x + hv.y * w1.y + hv.z * w1.z + hv.w * w1.w;
    ac += cv.x * w2.x + cv.y * w2.y + cv.z * w2.z + cv.w * w2.w;
  }
  decc0[b * 256 + tid] = ac;
  hh[tid] = ah;
  __syncthreads();
  if (tid < 128) {
    uint v = (uint)f2bu(hh[2 * tid]) | ((uint)f2bu(hh[2 * tid + 1]) << 16);
    Xd_u32[(size_t)b * 256 + tid] = v;          // h(0) packed
    Xd_u32[(size_t)b * 256 + 128 + tid] = 0u;   // O(-1) = 0
  }
}

// ---------------- decoder: 192 blocks; z precomputes h-part under att ---------
// id: g = id&7 (XCD), kb = id>>3. kb<8: z-block slice s (j in [32s,32s+32) x 4
// gates), Wl [128][520] (k<256: Whh, k>=256: WihO). acc carries zh(t) precomputed
// during att's phase; per step only the O-part MFMA (K=256) is on the critical
// path. kb>=8: att block b=8g+lb, O-half jh (unchanged from dec5).
// Xd: [par][b][256 uints] = [h(128u)|O(128u)] bf16-pair packed.
__global__ __launch_bounds__(512) void k_dec6(
    const float* __restrict__ YW, const float* __restrict__ dWih,
    const float* __restrict__ dWhh, const uint2* __restrict__ Wcq,
    const __hip_bfloat16* __restrict__ encproj_bf,
    const __hip_bfloat16* __restrict__ fwd_bf, const __hip_bfloat16* __restrict__ bwd_bf,
    const float* __restrict__ decc0, uint* __restrict__ Xd_u32,
    __hip_bfloat16* __restrict__ outs_bf,
    uint* __restrict__ zflags, uint* __restrict__ aflags) {
  __shared__ __align__(16) char smem[155648];
  const int id = blockIdx.x;
  const int g = id & 7, kb = id >> 3;
  const int tid = threadIdx.x;
  uint* zfl = zflags + (size_t)g * 8 * 32;
  uint* afl = aflags + (size_t)g * 16 * 32;

  if (kb < 8) {
    // ------------- z-block: split-K with zh precompute overlap ---------------
    const int s = kb;
    ushort* Wl = (ushort*)smem;                    // [128][520] = 133120 B
    ushort* Xa = (ushort*)(smem + 133120);         // [16][520] = 16640 B
    float* zslds = (float*)(smem + 149760);        // [8][128] = 4096 B
    float* hsb = (float*)(smem + 153856);          // [8][32] = 1024 B
    for (int i = tid; i < 128 * 512; i += 512) {
      int c = i >> 9, k2 = i & 511;
      int gate = c >> 5, jj = c & 31;
      int gr = gate * 256 + 32 * s + jj;
      float v = (k2 < 256) ? dWhh[(size_t)gr * 256 + k2]
                           : dWih[(size_t)gr * 512 + 256 + (k2 - 256)];
      Wl[c * 520 + k2] = f2bu(v);
    }
    for (int i = tid; i < 16 * 520; i += 512) Xa[i] = 0;
    const int lane = tid & 63, w = tid >> 6;  // 8 waves, wave = 16-col tile
    const int l15 = lane & 15, l4 = lane >> 4;
    float c_reg = 0.f;
    if (tid < 256) {
      int b = tid >> 5, jj = tid & 31;
      c_reg = decc0[(size_t)(8 * g + b) * 256 + 32 * s + jj];
    }
    __syncthreads();
    // prologue: stage h(0) from Xd[0].h, precompute zh(0)
    for (int i = tid; i < 8 * 128; i += 512) {
      int row = i >> 7, p = i & 127;
      uint v = ld_u32(Xd_u32 + (size_t)(8 * g + row) * 256 + p);
      *(uint*)&Xa[row * 520 + 2 * p] = v;
    }
    __syncthreads();
    f32x4 accv = (f32x4){0.f, 0.f, 0.f, 0.f};
    for (int kk = 0; kk < 8; kk++) {
      bf16x8 af = *(const bf16x8*)&Xa[l15 * 520 + kk * 32 + l4 * 8];
      bf16x8 bf = *(const bf16x8*)&Wl[(w * 16 + l15) * 520 + kk * 32 + l4 * 8];
      accv = __builtin_amdgcn_mfma_f32_16x16x32_bf16(af, bf, accv, 0, 0, 0);
    }
    for (int t = 0; t < 63; t++) {
      const int par = t & 1;
      // ---- wait O(t-1), stage it (t=0: already zero in Xd[0].O, no wait) ----
      if (t > 0) {
        if (tid < 16)
          while (ld_u32(&afl[tid * 32]) < (uint)t) __builtin_amdgcn_s_sleep(1);
        asm volatile("" ::: "memory");
        __syncthreads();
      }
      for (int i = tid; i < 8 * 128; i += 512) {
        int row = i >> 7, p = i & 127;
        uint v = ld_u32(Xd_u32 + (size_t)par * 16384 + (size_t)(8 * g + row) * 256 + 128 + p);
        *(uint*)&Xa[row * 520 + 256 + 2 * p] = v;
      }
      __syncthreads();
      // ---- O-part MFMA (K=256) accumulating onto zh(t) ----
      for (int kk = 8; kk < 16; kk++) {
        bf16x8 af = *(const bf16x8*)&Xa[l15 * 520 + kk * 32 + l4 * 8];
        bf16x8 bf = *(const bf16x8*)&Wl[(w * 16 + l15) * 520 + kk * 32 + l4 * 8];
        accv = __builtin_amdgcn_mfma_f32_16x16x32_bf16(af, bf, accv, 0, 0, 0);
      }
      if (l4 < 2) {
        #pragma unroll
        for (int r = 0; r < 4; r++) {
          int b = l4 * 4 + r;
          zslds[b * 128 + w * 16 + l15] = accv[r];
        }
      }
      __syncthreads();
      if (tid < 256) {  // LSTM gates + h for this slice (c in register)
        int b = tid >> 5, jj = tid & 31;
        int gb = 8 * g + b;
        const float* yw = YW + (size_t)(t * 64 + gb) * 1024 + 32 * s + jj;
        float zi = zslds[b * 128 + jj] + yw[0];
        float zf = zslds[b * 128 + 32 + jj] + yw[256];
        float zg = zslds[b * 128 + 64 + jj] + yw[512];
        float zo = zslds[b * 128 + 96 + jj] + yw[768];
        float c = sigf(zf) * c_reg + sigf(zi) * tanhfast(zg);
        c_reg = c;
        hsb[b * 32 + jj] = sigf(zo) * tanhfast(c);
      }
      __syncthreads();
      if (tid < 128) {  // packed uncached h-slice store -> Xd[par^1].h
        int b = tid >> 4, p = tid & 15;
        uint v = (uint)f2bu(hsb[b * 32 + 2 * p]) | ((uint)f2bu(hsb[b * 32 + 2 * p + 1]) << 16);
        st_u32(Xd_u32 + (size_t)(par ^ 1) * 16384 + (size_t)(8 * g + b) * 256 + 16 * s + p, v);
      }
      __syncthreads();  // drains vmcnt
      if (tid == 0) st_u32(&zfl[s * 32], (uint)(t + 1));
      // ---- overlap region: peer h exchange + zh(t+1) precompute -------------
      if (t < 62) {
        if (tid < 8)
          while (ld_u32(&zfl[tid * 32]) < (uint)(t + 1)) __builtin_amdgcn_s_sleep(1);
        asm volatile("" ::: "memory");
        __syncthreads();
        for (int i = tid; i < 8 * 128; i += 512) {
          int row = i >> 7, p = i & 127;
          uint v = ld_u32(Xd_u32 + (size_t)(par ^ 1) * 16384 + (size_t)(8 * g + row) * 256 + p);
          *(uint*)&Xa[row * 520 + 2 * p] = v;
        }
        __syncthreads();
        accv = (f32x4){0.f, 0.f, 0.f, 0.f};
        for (int kk = 0; kk < 8; kk++) {
          bf16x8 af = *(const bf16x8*)&Xa[l15 * 520 + kk * 32 + l4 * 8];
          bf16x8 bf = *(const bf16x8*)&Wl[(w * 16 + l15) * 520 + kk * 32 + l4 * 8];
          accv = __builtin_amdgcn_mfma_f32_16x16x32_bf16(af, bf, accv, 0, 0, 0);
        }
      }
    }
  } else {
    // ------------- attention block: b = 8g+lb, O-half jh ----------------------
    const int lb = (kb - 8) >> 1, jh = (kb - 8) & 1;
    const int b = 8 * g + lb;
    ushort* ep = (ushort*)smem;                    // [64][264] = 33792 B
    ushort* eh = (ushort*)(smem + 33792);          // [64][520] = 66560 B
    float* hn = (float*)(smem + 100352);           // 256 f
    float* xcomb = (float*)(smem + 101376);        // 768 f
    float* e_l = (float*)(smem + 104448);          // 64
    float* alpha_l = (float*)(smem + 104704);      // 64
    float* op_l = (float*)(smem + 104960);         // [4][128] f
    float* Ost = (float*)(smem + 107008);          // 128 f
    for (int i = tid; i < 64 * 256; i += 512) {
      int s2 = i >> 8, k2 = i & 255;
      ep[s2 * 264 + k2] = ((const ushort*)encproj_bf)[(size_t)(b * 64 + s2) * 256 + k2];
    }
    for (int i = tid; i < 64 * 512; i += 512) {
      int s2 = i >> 9, d = i & 511;
      ushort v = (d < 256) ? ((const ushort*)fwd_bf)[(size_t)(s2 * 64 + b) * 256 + d]
                           : ((const ushort*)bwd_bf)[(size_t)(s2 * 64 + b) * 256 + d - 256];
      eh[s2 * 520 + d] = v;
    }
    __syncthreads();
    for (int t = 0; t < 63; t++) {
      if (tid < 8)
        while (ld_u32(&zfl[tid * 32]) < (uint)(t + 1)) __builtin_amdgcn_s_sleep(1);
      asm volatile("" ::: "memory");
      __syncthreads();
      if (tid < 128) {  // stage h(t+1) (uncached, packed)
        uint v = ld_u32(Xd_u32 + (size_t)((t & 1) ^ 1) * 16384 + (size_t)b * 256 + tid);
        hn[2 * tid] = bflo(v);
        hn[2 * tid + 1] = bfhi(v);
      }
      __syncthreads();
      {  // e[s]
        int s2 = tid >> 3, q8 = tid & 7;
        const ushort* pr = ep + s2 * 264 + q8 * 32;
        const float* hq = hn + q8 * 32;
        float a = 0.f;
        #pragma unroll 8
        for (int kk = 0; kk < 32; kk += 2) {
          uint wv = *(const uint*)(pr + kk);
          a += bflo(wv) * hq[kk] + bfhi(wv) * hq[kk + 1];
        }
        a += __shfl_xor(a, 1);
        a += __shfl_xor(a, 2);
        a += __shfl_xor(a, 4);
        if (q8 == 0) e_l[s2] = a;
      }
      __syncthreads();
      if (tid < 64) {
        float e = e_l[tid];
        float mx = e;
        #pragma unroll
        for (int o = 32; o > 0; o >>= 1) mx = fmaxf(mx, __shfl_xor(mx, o));
        float p = __expf(e - mx);
        float ss = p;
        #pragma unroll
        for (int o = 32; o > 0; o >>= 1) ss += __shfl_xor(ss, o);
        alpha_l[tid] = p / ss;
      }
      __syncthreads();
      {  // a_t[d]
        float a = 0.f;
        const ushort* col = eh + tid;
        #pragma unroll 8
        for (int s2 = 0; s2 < 64; s2++)
          a += alpha_l[s2] * __uint_as_float(((uint)col[s2 * 520]) << 16);
        xcomb[tid] = a;
        if (tid < 256) xcomb[512 + tid] = hn[tid];
      }
      __syncthreads();
      {  // O-half = tanh(xcomb . Wcomb^T), stream Wcq half (L2-resident)
        int jl = tid & 127, kq = tid >> 7;
        int j = jh * 128 + jl;
        const uint2* wp = Wcq + (size_t)(kq * 48) * 256 + j;
        const float4* x4 = (const float4*)xcomb + kq * 48;
        float a = 0.f;
        #pragma unroll 6
        for (int ii = 0; ii < 48; ii++) {
          uint2 wv = wp[(size_t)ii * 256];
          float4 xv = x4[ii];
          a += bflo(wv.x) * xv.x + bfhi(wv.x) * xv.y + bflo(wv.y) * xv.z + bfhi(wv.y) * xv.w;
        }
        op_l[kq * 128 + jl] = a;
      }
      __syncthreads();
      if (tid < 128) {
        float sum = op_l[tid] + op_l[128 + tid] + op_l[256 + tid] + op_l[384 + tid];
        float O = tanhfast(sum);
        Ost[tid] = O;
        ((ushort*)outs_bf)[(size_t)(t * 64 + b) * 256 + jh * 128 + tid] = f2bu(O);
      }
      __syncthreads();
      if (tid < 64) {  // packed uncached O store -> Xd[par^1].O
        uint v = (uint)f2bu(Ost[2 * tid]) | ((uint)f2bu(Ost[2 * tid + 1]) << 16);
        st_u32(Xd_u32 + (size_t)((t & 1) ^ 1) * 16384 + (size_t)b * 256 + 128 + jh * 64 + tid, v);
      }
      __syncthreads();  // drains vmcnt
      if (tid == 0) st_u32(&afl[(lb * 2 + jh) * 32], (uint)(t + 1));
    }
  }
}

// ---------------- final reduce ------------------------------------------------
__global__ __launch_bounds__(256) void k_final(
    const float* __restrict__ part_max, const float* __restrict__ part_sum,
    const float* __restrict__ gold, const int* __restrict__ tgt,
    float* __restrict__ out) {
  int b = blockIdx.x, tid = threadIdx.x;
  int tq = tid >> 2, q = tid & 3;
  __shared__ float lm[64][4], ls[64][4];
  __shared__ float red[64];
  if (tq < T - 1) {
    int n = tq * B + b;
    float m = -__builtin_inff(), s = 0;
    for (int i = q; i < NCHUNK; i += 4) {
      float pmv = part_max[(size_t)i * NROW + n];
      float psv = part_sum[(size_t)i * NROW + n];
      float M2 = fmaxf(m, pmv);
      s = s * __expf(m - M2) + psv * __expf(pmv - M2);
      m = M2;
    }
    lm[tq][q] = m;
    ls[tq][q] = s;
  }
  __syncthreads();
  if (tid < T - 1) {
    float M = fmaxf(fmaxf(lm[tid][0], lm[tid][1]), fmaxf(lm[tid][2], lm[tid][3]));
    float Ss = ls[tid][0] * __expf(lm[tid][0] - M) + ls[tid][1] * __expf(lm[tid][1] - M) +
               ls[tid][2] * __expf(lm[tid][2] - M) + ls[tid][3] * __expf(lm[tid][3] - M);
    float lse = M + logf(Ss);
    int g = tgt[(tid + 1) * B + b];
    red[tid] = (g != 0) ? (gold[tid * B + b] - lse) : 0.f;
  }
  if (tid == T - 1) red[T - 1] = 0.f;
  __syncthreads();
  if (tid == 0) {
    float s = 0;
    for (int i = 0; i < T - 1; i++) s += red[i];
    out[b] = s;
  }
}

extern "C" void kernel_launch(void* const* d_in, const int* in_sizes, int n_in,
                              void* d_out, int out_size, void* d_ws, size_t ws_size,
                              hipStream_t stream) {
  (void)in_sizes; (void)n_in; (void)out_size; (void)ws_size;
  const int*   src   = (const int*)  d_in[0];
  const int*   tgt   = (const int*)  d_in[1];
  const float* semb  = (const float*)d_in[2];
  const float* temb  = (const float*)d_in[3];
  const float* WihF  = (const float*)d_in[4];
  const float* WhhF  = (const float*)d_in[5];
  const float* bF    = (const float*)d_in[6];
  const float* WihB  = (const float*)d_in[7];
  const float* WhhB  = (const float*)d_in[8];
  const float* bB    = (const float*)d_in[9];
  const float* dWih  = (const float*)d_in[10];
  const float* dWhh  = (const float*)d_in[11];
  const float* db    = (const float*)d_in[12];
  const float* Wh    = (const float*)d_in[13];
  const float* Wc    = (const float*)d_in[14];
  const float* Watt  = (const float*)d_in[15];
  const float* Wcomb = (const float*)d_in[16];
  const float* Wv    = (const float*)d_in[17];
  float* out = (float*)d_out;

  char* wp = (char*)d_ws;
  auto alloc = [&](size_t bytes) -> char* {
    char* p = wp;
    wp += (bytes + 255) & ~(size_t)255;
    return p;
  };
  float* XwF  = (float*)alloc((size_t)S * B * H4 * 4);
  float* XwB  = (float*)alloc((size_t)S * B * H4 * 4);
  float* YW   = (float*)alloc((size_t)(T - 1) * B * H4 * 4);
  __hip_bfloat16* fwd_bf     = (__hip_bfloat16*)alloc((size_t)S * B * H * 2);
  __hip_bfloat16* bwd_bf     = (__hip_bfloat16*)alloc((size_t)S * B * H * 2);
  __hip_bfloat16* encproj_bf = (__hip_bfloat16*)alloc((size_t)B * S * H * 2);
  __hip_bfloat16* Ag         = (__hip_bfloat16*)alloc((size_t)S * B * E * 2);
  __hip_bfloat16* Yg         = (__hip_bfloat16*)alloc((size_t)(T - 1) * B * E * 2);
  __hip_bfloat16* WihF_bf    = (__hip_bfloat16*)alloc((size_t)H4 * E * 2);
  __hip_bfloat16* WihB_bf    = (__hip_bfloat16*)alloc((size_t)H4 * E * 2);
  __hip_bfloat16* dWih_bf    = (__hip_bfloat16*)alloc((size_t)H4 * E * 2);
  __hip_bfloat16* Wv_bf      = (__hip_bfloat16*)alloc((size_t)V * H * 2);
  __hip_bfloat16* Watt_bf    = (__hip_bfloat16*)alloc((size_t)H * 512 * 2);
  __hip_bfloat16* outs_bf    = (__hip_bfloat16*)alloc((size_t)NROW * H * 2);
  uint2* Wcq = (uint2*)alloc((size_t)192 * 256 * 8);
  float* part_max = (float*)alloc((size_t)NCHUNK * NROW * 4);
  float* part_sum = (float*)alloc((size_t)NCHUNK * NROW * 4);
  float* gold     = (float*)alloc((size_t)NROW * 4);
  float* Cfin  = (float*)alloc((size_t)2 * B * H * 4);
  float* decc0 = (float*)alloc((size_t)B * H * 4);
  __hip_bfloat16* Xenc = (__hip_bfloat16*)alloc((size_t)2 * 2 * B * H * 2);  // [par][dir][b][j]
  uint* Xdec = (uint*)alloc((size_t)2 * B * 256 * 4);                        // [par][b][h|O] packed
  // state: flags, zeroed every call
  char* stateBase = wp;
  uint* eflags = (uint*)alloc(16 * 8 * 32 * 4);
  uint* zflags = (uint*)alloc(8 * 8 * 32 * 4);
  uint* aflags = (uint*)alloc(8 * 16 * 32 * 4);
  size_t stateBytes = (size_t)(wp - stateBase);
  hipMemsetAsync(stateBase, 0, stateBytes, stream);
  hipMemsetAsync(Xenc, 0, (size_t)2 * 2 * B * H * 2, stream);

  // converts + gathers + packs
  hipLaunchKernelGGL(k_cvt_bf16, dim3((H4 * E + 255) / 256), dim3(256), 0, stream,
                     WihF, WihF_bf, H4 * E);
  hipLaunchKernelGGL(k_cvt_bf16, dim3((H4 * E + 255) / 256), dim3(256), 0, stream,
                     WihB, WihB_bf, H4 * E);
  hipLaunchKernelGGL(k_cvt_slice, dim3(H4), dim3(256), 0, stream, dWih, dWih_bf);
  hipLaunchKernelGGL(k_cvt_bf16, dim3((V * H + 255) / 256), dim3(256), 0, stream,
                     Wv, Wv_bf, V * H);
  hipLaunchKernelGGL(k_cvt_bf16, dim3((H * 512 + 255) / 256), dim3(256), 0, stream,
                     Watt, Watt_bf, H * 512);
  hipLaunchKernelGGL(k_gather, dim3(S * B), dim3(256), 0, stream, src, semb, Ag);
  hipLaunchKernelGGL(k_gather, dim3((T - 1) * B), dim3(256), 0, stream, tgt, temb, Yg);
  hipLaunchKernelGGL(k_pack4, dim3(192 * 256 / 256), dim3(256), 0, stream,
                     Wcomb, Wcq, 192 * 256, 8, 768, 0);

  // input GEMMs (MFMA)
  hipLaunchKernelGGL(k_gemm_bias, dim3(H4 / 64, S * B / 64), dim3(256), 0, stream,
                     Ag, WihF_bf, bF, XwF, H4);
  hipLaunchKernelGGL(k_gemm_bias, dim3(H4 / 64, S * B / 64), dim3(256), 0, stream,
                     Ag, WihB_bf, bB, XwB, H4);
  hipLaunchKernelGGL(k_gemm_bias, dim3(H4 / 64, (T - 1) * B / 64), dim3(256), 0, stream,
                     Yg, dWih_bf, db, YW, H4);

  // encoder: 128 blocks, XCD-local octets, uncached exchange
  hipLaunchKernelGGL(k_enc4, dim3(128), dim3(256), 0, stream,
                     XwF, XwB, WhhF, WhhB, (uint*)Xenc, fwd_bf, bwd_bf, Cfin, eflags);
  hipLaunchKernelGGL(k_dec_init3, dim3(B), dim3(256), 0, stream,
                     Xenc, Cfin, Wh, Wc, Xdec, decc0);
  hipLaunchKernelGGL(k_encproj_mfma, dim3(4, 64), dim3(256), 0, stream,
                     fwd_bf, bwd_bf, Watt_bf, encproj_bf);

  // decoder: 192 blocks (64 z + 128 attention), zh-precompute overlap
  hipLaunchKernelGGL(k_dec6, dim3(192), dim3(512), 0, stream,
                     YW, dWih, dWhh, Wcq, encproj_bf, fwd_bf, bwd_bf,
                     decc0, Xdec, outs_bf, zflags, aflags);

  // vocab projection (B-stationary) + final reduce
  hipLaunchKernelGGL(k_vocab2, dim3(NCHUNK), dim3(256), 0, stream,
                     outs_bf, Wv_bf, tgt, part_max, part_sum, gold);
  hipLaunchKernelGGL(k_final, dim3(B), dim3(256), 0, stream,
                     part_max, part_sum, gold, tgt, out);
}